// Round 10
// baseline (383.492 us; speedup 1.0000x reference)
//
#include <hip/hip_runtime.h>
#include <stdint.h>

// Problem: B=4, S=2048, D_IN=1024, H=1024; fp32 in/out.
// R15: 128^2 core + mask compaction (key mask kills whole columns). 414->382.
// R16: scores live-prefix decode 91->82.6us (one-shot kernels are issue-
//      starved at ~1.3 blocks/CU; prefix gives 2/CU).
// R17: proj merge FAILED (136.5us @ 26.6% MfmaUtil vs ~127 split) -- mixed
//      block types dilute L2 panel reuse; backfill alone is not R0's 40%
//      mechanism. scores XCD affinity measured positive. Net flat (369).
// R18: consolidation. (a) proj back to 3 homogeneous launches. (b) merge the
//      three independent FRONT kernels (prep/split/splitWT -- all streaming,
//      no panel competition) into one launch: -2 inter-kernel gaps (~80-95us
//      total lives between 7 sequential dispatches). (c) plain-core kernels
//      (32KB LDS) get __launch_bounds__(256,4) -> 4 blocks/CU capacity
//      (proj_v, pv). (d) scores keeps XCD-affine prefix; tail extended to
//      bx<=15 (dead blocks are free; robust to cnt>1152).
// R18b: resubmission -- previous round died in infra (container failed
//      twice, no counters); source re-audited (no hang/OOB/VGPR risk) and
//      unchanged.

#define S_LEN 2048
#define BATCH 4
#define DIN   1024
#define HDIM  1024
#define N3H   3072
#define NTOK  8192   // BATCH*S_LEN

typedef unsigned short u16;
typedef __attribute__((ext_vector_type(8))) short bf16x8;
typedef __attribute__((ext_vector_type(4))) float f32x4;
typedef __attribute__((ext_vector_type(16))) float f32x16;
typedef __attribute__((ext_vector_type(4))) unsigned short u16x4;

// ---------- bf16 helpers (bit ops, RN) ----------
__device__ __forceinline__ u16 f2bf(float x) {
  union { float f; unsigned u; } c; c.f = x;
  unsigned r = c.u + 0x7fffu + ((c.u >> 16) & 1u);
  return (u16)(r >> 16);
}
__device__ __forceinline__ float bf2f(u16 h) {
  union { unsigned u; float f; } c; c.u = ((unsigned)h) << 16;
  return c.f;
}

// ---------- async global->LDS, width 16 ----------
__device__ __forceinline__ void gload16(const void* g, void* lds) {
  auto* gp = reinterpret_cast<const __attribute__((address_space(1))) void*>(
      reinterpret_cast<uintptr_t>(g));
  auto* lp = reinterpret_cast<__attribute__((address_space(3))) void*>(
      (unsigned)reinterpret_cast<uintptr_t>(lds));
  __builtin_amdgcn_global_load_lds(gp, lp, 16, 0, 0);
}

// Stage a 128x64 bf16 tile (row-major, row stride ld elems) into swizzled LDS.
// Layout: element (row, kb=k/8) at byte row*128 + ((kb ^ (row&7))*16).
__device__ __forceinline__ void stage_tile(const u16* __restrict__ g, int ld,
                                           u16* lds, int wave, int lane) {
  const int rlane = lane >> 3;                       // 0..7: row within instr
  const int kb    = (lane & 7) ^ (rlane & 7);        // swizzled k-block
#pragma unroll
  for (int h = 0; h < 4; ++h) {
    const int instr = wave * 4 + h;                  // 0..15
    const u16* gp = g + (size_t)(instr * 8 + rlane) * ld + kb * 8;
    gload16(gp, (char*)lds + instr * 1024);
  }
}

// Indirect-row variant: rows come from idxb[jbase + r] (compact -> token).
__device__ __forceinline__ void stage_tile_idx(
    const u16* __restrict__ gbase, const int* __restrict__ idxb, int jbase,
    int k0, u16* lds, int wave, int lane) {
  const int rlane = lane >> 3;
  const int kb    = (lane & 7) ^ (rlane & 7);
#pragma unroll
  for (int h = 0; h < 4; ++h) {
    const int instr = wave * 4 + h;
    const int s = idxb[jbase + instr * 8 + rlane];   // original token row
    const u16* gp = gbase + (size_t)s * DIN + k0 + kb * 8;
    gload16(gp, (char*)lds + instr * 1024);
  }
}

// 32x32x16 fragment fetch from swizzled [128][64] LDS tile.
// A-operand layout: A[m=lane&31][k=(lane>>5)*8+j] (R5/R6-verified).
__device__ __forceinline__ bf16x8 frag32(const u16* t, int wq, int sub, int kh,
                                         int lane) {
  const int r5   = lane & 31;
  const int row  = wq * 64 + sub * 32 + r5;
  const int slot = (kh * 2 + (lane >> 5)) ^ (r5 & 7);
  return *(const bf16x8*)(t + row * 64 + slot * 8);
}

// ---------- split-precision gemm_bt core: C(128x128) += (Ah+Al)*(Bh+Bl)^T ----------
// lds: 64KB (4 x 16KB regions) provided by the caller.
__device__ __forceinline__ void gemm_core_split(
    u16* lds,
    const u16* __restrict__ Ah, const u16* __restrict__ Al,
    const u16* __restrict__ Bh, const u16* __restrict__ Bl,
    int lda, int ldb, int K, f32x16 acc[2][2])
{
  u16* aH = lds;           u16* aL = lds + 8192;
  u16* bH = lds + 16384;   u16* bL = lds + 24576;
  const int tid  = threadIdx.x;
  const int wave = tid >> 6, lane = tid & 63;
  const int wm = wave >> 1, wn = wave & 1;

#pragma unroll
  for (int i = 0; i < 2; ++i)
#pragma unroll
    for (int j = 0; j < 2; ++j)
#pragma unroll
      for (int r = 0; r < 16; ++r) acc[i][j][r] = 0.f;

  for (int k0 = 0; k0 < K; k0 += 64) {
    stage_tile(Ah + k0, lda, aH, wave, lane);
    stage_tile(Al + k0, lda, aL, wave, lane);
    stage_tile(Bh + k0, ldb, bH, wave, lane);
    stage_tile(Bl + k0, ldb, bL, wave, lane);
    __syncthreads();   // drains vmcnt (global_load_lds) before LDS reads

#pragma unroll
    for (int kh = 0; kh < 4; ++kh) {
      bf16x8 fah[2], fal[2];
#pragma unroll
      for (int i = 0; i < 2; ++i) {
        fah[i] = frag32(aH, wm, i, kh, lane);
        fal[i] = frag32(aL, wm, i, kh, lane);
      }
#pragma unroll
      for (int j = 0; j < 2; ++j) {
        const bf16x8 fbh = frag32(bH, wn, j, kh, lane);
        const bf16x8 fbl = frag32(bL, wn, j, kh, lane);
#pragma unroll
        for (int i = 0; i < 2; ++i) {
          acc[i][j] = __builtin_amdgcn_mfma_f32_32x32x16_bf16(fah[i], fbh, acc[i][j], 0, 0, 0);
          acc[i][j] = __builtin_amdgcn_mfma_f32_32x32x16_bf16(fah[i], fbl, acc[i][j], 0, 0, 0);
          acc[i][j] = __builtin_amdgcn_mfma_f32_32x32x16_bf16(fal[i], fbh, acc[i][j], 0, 0, 0);
        }
      }
    }
    __syncthreads();   // protect LDS before next stage
  }
}

// Same core, A rows fetched through idx (compact rows jbase..jbase+127).
__device__ __forceinline__ void gemm_core_split_idx(
    u16* lds,
    const u16* __restrict__ Ah, const u16* __restrict__ Al,  // batch base
    const int* __restrict__ idxb, int jbase,
    const u16* __restrict__ Bh, const u16* __restrict__ Bl,
    f32x16 acc[2][2])
{
  u16* aH = lds;           u16* aL = lds + 8192;
  u16* bH = lds + 16384;   u16* bL = lds + 24576;
  const int tid  = threadIdx.x;
  const int wave = tid >> 6, lane = tid & 63;
  const int wm = wave >> 1, wn = wave & 1;

#pragma unroll
  for (int i = 0; i < 2; ++i)
#pragma unroll
    for (int j = 0; j < 2; ++j)
#pragma unroll
      for (int r = 0; r < 16; ++r) acc[i][j][r] = 0.f;

  for (int k0 = 0; k0 < DIN; k0 += 64) {
    stage_tile_idx(Ah, idxb, jbase, k0, aH, wave, lane);
    stage_tile_idx(Al, idxb, jbase, k0, aL, wave, lane);
    stage_tile(Bh + k0, DIN, bH, wave, lane);
    stage_tile(Bl + k0, DIN, bL, wave, lane);
    __syncthreads();

#pragma unroll
    for (int kh = 0; kh < 4; ++kh) {
      bf16x8 fah[2], fal[2];
#pragma unroll
      for (int i = 0; i < 2; ++i) {
        fah[i] = frag32(aH, wm, i, kh, lane);
        fal[i] = frag32(aL, wm, i, kh, lane);
      }
#pragma unroll
      for (int j = 0; j < 2; ++j) {
        const bf16x8 fbh = frag32(bH, wn, j, kh, lane);
        const bf16x8 fbl = frag32(bL, wn, j, kh, lane);
#pragma unroll
        for (int i = 0; i < 2; ++i) {
          acc[i][j] = __builtin_amdgcn_mfma_f32_32x32x16_bf16(fah[i], fbh, acc[i][j], 0, 0, 0);
          acc[i][j] = __builtin_amdgcn_mfma_f32_32x32x16_bf16(fah[i], fbl, acc[i][j], 0, 0, 0);
          acc[i][j] = __builtin_amdgcn_mfma_f32_32x32x16_bf16(fal[i], fbh, acc[i][j], 0, 0, 0);
        }
      }
    }
    __syncthreads();
  }
}

// ---------- plain bf16 gemm_bt core (lds: 32KB) ----------
__device__ __forceinline__ void gemm_core_plain(
    u16* lds,
    const u16* __restrict__ A, const u16* __restrict__ B,
    int lda, int ldb, int K, f32x16 acc[2][2])
{
  u16* aT = lds; u16* bT = lds + 8192;
  const int tid  = threadIdx.x;
  const int wave = tid >> 6, lane = tid & 63;
  const int wm = wave >> 1, wn = wave & 1;

#pragma unroll
  for (int i = 0; i < 2; ++i)
#pragma unroll
    for (int j = 0; j < 2; ++j)
#pragma unroll
      for (int r = 0; r < 16; ++r) acc[i][j][r] = 0.f;

  for (int k0 = 0; k0 < K; k0 += 64) {
    stage_tile(A + k0, lda, aT, wave, lane);
    stage_tile(B + k0, ldb, bT, wave, lane);
    __syncthreads();
#pragma unroll
    for (int kh = 0; kh < 4; ++kh) {
      bf16x8 fa[2];
#pragma unroll
      for (int i = 0; i < 2; ++i) fa[i] = frag32(aT, wm, i, kh, lane);
#pragma unroll
      for (int j = 0; j < 2; ++j) {
        const bf16x8 fb = frag32(bT, wn, j, kh, lane);
#pragma unroll
        for (int i = 0; i < 2; ++i)
          acc[i][j] = __builtin_amdgcn_mfma_f32_32x32x16_bf16(fa[i], fb, acc[i][j], 0, 0, 0);
      }
    }
    __syncthreads();
  }
}

// Plain core, A rows via idx (for proj V), lda = DIN implicit.
__device__ __forceinline__ void gemm_core_plain_idx(
    u16* lds,
    const u16* __restrict__ A, const int* __restrict__ idxb, int jbase,
    const u16* __restrict__ B, f32x16 acc[2][2])
{
  u16* aT = lds; u16* bT = lds + 8192;
  const int tid  = threadIdx.x;
  const int wave = tid >> 6, lane = tid & 63;
  const int wm = wave >> 1, wn = wave & 1;

#pragma unroll
  for (int i = 0; i < 2; ++i)
#pragma unroll
    for (int j = 0; j < 2; ++j)
#pragma unroll
      for (int r = 0; r < 16; ++r) acc[i][j][r] = 0.f;

  for (int k0 = 0; k0 < DIN; k0 += 64) {
    stage_tile_idx(A, idxb, jbase, k0, aT, wave, lane);
    stage_tile(B + k0, DIN, bT, wave, lane);
    __syncthreads();
#pragma unroll
    for (int kh = 0; kh < 4; ++kh) {
      bf16x8 fa[2];
#pragma unroll
      for (int i = 0; i < 2; ++i) fa[i] = frag32(aT, wm, i, kh, lane);
#pragma unroll
      for (int j = 0; j < 2; ++j) {
        const bf16x8 fb = frag32(bT, wn, j, kh, lane);
#pragma unroll
        for (int i = 0; i < 2; ++i)
          acc[i][j] = __builtin_amdgcn_mfma_f32_32x32x16_bf16(fa[i], fb, acc[i][j], 0, 0, 0);
      }
    }
    __syncthreads();
  }
}

// C/D layout for 32x32 (HW-verified m74/m101):
//   col = lane&31, row = (reg&3) + 8*(reg>>2) + 4*(lane>>5)
#define ROW32(r, lane) (((r) & 3) + 8 * ((r) >> 2) + 4 * ((lane) >> 5))

// ---------- front: split qkv + transpose/split W + mask compaction, ONE launch ----------
// ids [0,8192): split_f32 ; [8192,11264): splitWT ; 11264: prep/compact.
// All streaming/BW-bound, independent outputs -> safe to co-schedule (R17's
// merge lesson applies to GEMM blocks competing for L2 panels, not these).
// Branch is uniform per block (on blockIdx), so in-branch __syncthreads is safe.
__global__ __launch_bounds__(256) void front_kernel(
    const float* __restrict__ qkv, const float* __restrict__ W,
    const unsigned char* __restrict__ m,
    u16* __restrict__ ahi, u16* __restrict__ alo,
    u16* __restrict__ whi, u16* __restrict__ wlo,
    int* __restrict__ idx, int* __restrict__ kcount)
{
  __shared__ float tile[32][33];
  __shared__ int isBool;
  const int id = blockIdx.x;
  const int t = threadIdx.x;

  if (id < 8192) {                       // ---- split fp32 -> bf16 hi/lo ----
    const int i = (id * 256 + t) * 4;
    const f32x4 v = *(const f32x4*)(qkv + i);
    u16x4 h, l;
#pragma unroll
    for (int c = 0; c < 4; ++c) {
      h[c] = f2bf(v[c]);
      l[c] = f2bf(v[c] - bf2f(h[c]));
    }
    *(u16x4*)(ahi + i) = h;
    *(u16x4*)(alo + i) = l;
  } else if (id < 11264) {               // ---- transpose + split W ----
    const int wid = id - 8192;           // 0..3071
    const int n0 = (wid % 96) * 32;
    const int d0 = (wid / 96) * 32;
    const int dr = t >> 3, nc = (t & 7) * 4;
    const f32x4 v = *(const f32x4*)(W + (size_t)(d0 + dr) * N3H + n0 + nc);
#pragma unroll
    for (int c = 0; c < 4; ++c) tile[dr][nc + c] = v[c];
    __syncthreads();
    const int nr = t >> 3, dc = (t & 7) * 4;
    u16x4 h, l;
#pragma unroll
    for (int c = 0; c < 4; ++c) {
      const float x = tile[dc + c][nr];
      h[c] = f2bf(x);
      l[c] = f2bf(x - bf2f(h[c]));
    }
    const size_t o = (size_t)(n0 + nr) * DIN + d0 + dc;
    *(u16x4*)(whi + o) = h;
    *(u16x4*)(wlo + o) = l;
  } else {                               // ---- prep: repr-detect + compact scan ----
    if (t == 0) isBool = 0;
    __syncthreads();
    for (int i = t; i < NTOK; i += 256)
      if ((i & 3) && m[i]) isBool = 1;   // int32 repr of 0/1 has zero bytes at %4!=0
    __syncthreads();
    const int stride = isBool ? 1 : 4;
    const int wave = t >> 6, lane = t & 63;
    const int b = wave;                  // 4 waves, one batch each
    const int base = b * S_LEN;
    int running = 0;
#pragma unroll 1
    for (int c = 0; c < S_LEN / 64; ++c) {
      const int s = c * 64 + lane;
      const int um = (m[(size_t)(base + s) * stride] == 0);   // unmasked key
      const unsigned long long bal = __ballot(um);
      const int pre = (int)__popcll(bal & ((1ULL << lane) - 1ULL));
      if (um) idx[base + running + pre] = s;
      running += (int)__popcll(bal);     // wave-uniform
    }
    if (lane == 0) kcount[b] = running;
    for (int j = running + lane; j < S_LEN; j += 64) idx[base + j] = 0;
  }
}

// ---------- projection GEMM (Q third): split precision, full rows ----------
__global__ __launch_bounds__(256, 2) void proj_q_kernel(
    const u16* __restrict__ Ahi, const u16* __restrict__ Alo,
    const u16* __restrict__ Whi, const u16* __restrict__ Wlo,
    const float* __restrict__ bias,
    u16* __restrict__ qhi, u16* __restrict__ qlo)
{
  __shared__ __align__(16) u16 lds[4 * 8192];
  const int bx = blockIdx.x, by = blockIdx.y;  // bx 0..7 (Q cols), by 0..63
  f32x16 acc[2][2];
  gemm_core_split(lds,
                  Ahi + (size_t)by * 128 * DIN, Alo + (size_t)by * 128 * DIN,
                  Whi + (size_t)bx * 128 * DIN, Wlo + (size_t)bx * 128 * DIN,
                  DIN, DIN, DIN, acc);
  const int lane = threadIdx.x & 63, wave = threadIdx.x >> 6;
  const int wm = wave >> 1, wn = wave & 1;
#pragma unroll
  for (int i = 0; i < 2; ++i) {
#pragma unroll
    for (int j = 0; j < 2; ++j) {
#pragma unroll
      for (int r = 0; r < 16; ++r) {
        const int row = by * 128 + wm * 64 + i * 32 + ROW32(r, lane);  // token
        const int col = bx * 128 + wn * 64 + j * 32 + (lane & 31);     // 0..1023
        const float v = acc[i][j][r] + bias[col];
        const u16 h = f2bf(v);
        const u16 l = f2bf(v - bf2f(h));
        const size_t o = (size_t)row * HDIM + col;
        qhi[o] = h; qlo[o] = l;
      }
    }
  }
}

// ---------- projection GEMM (K third): split, compacted rows ----------
// 1D grid 512, t slow-major: live ids form a prefix (t*128 < cnt).
__global__ __launch_bounds__(256, 2) void proj_k_kernel(
    const u16* __restrict__ Ahi, const u16* __restrict__ Alo,
    const u16* __restrict__ Whi, const u16* __restrict__ Wlo,
    const float* __restrict__ bias,
    const int* __restrict__ idx, const int* __restrict__ kcount,
    u16* __restrict__ khi, u16* __restrict__ klo)
{
  __shared__ __align__(16) u16 lds[4 * 8192];
  const int id = blockIdx.x;           // 0..511
  const int t  = id >> 5;              // compact-row tile 0..15 (slow axis)
  const int rs = id & 31;
  const int b  = rs >> 3;              // batch
  const int bx = rs & 7;               // K-col tile
  const int cnt = kcount[b];
  if (t * 128 >= cnt) return;          // dead tile

  f32x16 acc[2][2];
  gemm_core_split_idx(lds,
                      Ahi + (size_t)b * S_LEN * DIN, Alo + (size_t)b * S_LEN * DIN,
                      idx + b * S_LEN, t * 128,
                      Whi + (size_t)(HDIM + bx * 128) * DIN,
                      Wlo + (size_t)(HDIM + bx * 128) * DIN, acc);
  const int lane = threadIdx.x & 63, wave = threadIdx.x >> 6;
  const int wm = wave >> 1, wn = wave & 1;
#pragma unroll
  for (int i = 0; i < 2; ++i) {
#pragma unroll
    for (int j = 0; j < 2; ++j) {
#pragma unroll
      for (int r = 0; r < 16; ++r) {
        const int jl   = t * 128 + wm * 64 + i * 32 + ROW32(r, lane);  // compact row
        const int hcol = bx * 128 + wn * 64 + j * 32 + (lane & 31);
        const float v = acc[i][j][r] + bias[HDIM + hcol];
        const u16 h = f2bf(v);
        const u16 l = f2bf(v - bf2f(h));
        const size_t o = ((size_t)b * S_LEN + jl) * HDIM + hcol;
        khi[o] = h; klo[o] = l;
      }
    }
  }
}

// ---------- projection GEMM (V third): plain bf16, compacted, V transposed ----------
// 32KB LDS -> (256,4): 4 blocks/CU capacity for stall absorption.
__global__ __launch_bounds__(256, 4) void proj_v_kernel(
    const u16* __restrict__ Ahi, const u16* __restrict__ Whi,
    const float* __restrict__ bias,
    const int* __restrict__ idx, const int* __restrict__ kcount,
    u16* __restrict__ vt)
{
  __shared__ __align__(16) u16 lds[2 * 8192];
  const int id = blockIdx.x;           // 0..511
  const int t  = id >> 5;
  const int rs = id & 31;
  const int b  = rs >> 3;
  const int bx = rs & 7;               // H-col tile
  const int cnt = kcount[b];
  if (t * 128 >= cnt) return;

  f32x16 acc[2][2];
  gemm_core_plain_idx(lds,
                      Ahi + (size_t)b * S_LEN * DIN, idx + b * S_LEN, t * 128,
                      Whi + (size_t)(2048 + bx * 128) * DIN, acc);
  const int lane = threadIdx.x & 63, wave = threadIdx.x >> 6;
  const int wm = wave >> 1, wn = wave & 1;
#pragma unroll
  for (int i = 0; i < 2; ++i) {
#pragma unroll
    for (int j = 0; j < 2; ++j) {
#pragma unroll
      for (int r = 0; r < 16; ++r) {
        const int jl   = t * 128 + wm * 64 + i * 32 + ROW32(r, lane);  // compact col
        const int hcol = bx * 128 + wn * 64 + j * 32 + (lane & 31);
        const float v = acc[i][j][r] + bias[2 * HDIM + hcol];
        vt[((size_t)b * HDIM + hcol) * S_LEN + jl] = f2bf(v);
      }
    }
  }
}

// ---------- scores GEMM: sc = 32 * Q @ Kc^T (compact keys) ----------
// XCD-affine prefix decode (R17, measured positive): ids<512 have bx=id&7 ->
// each XCD owns ONE live K-stripe (2MB hi+lo, L2-pinned), walks all (b,by).
// ids 512..1023: bx=8..15 tails (dead unless cnt>bx*128; dead blocks free).
__global__ __launch_bounds__(256, 2) void scores_kernel(
    const u16* __restrict__ qhi, const u16* __restrict__ qlo,
    const u16* __restrict__ khi, const u16* __restrict__ klo,
    const int* __restrict__ kcount, float* __restrict__ scores)
{
  __shared__ __align__(16) u16 lds[4 * 8192];
  const int id = blockIdx.x;            // 0..1023
  int b, by, bx;
  if (id < 512) { bx = id & 7; const int r = id >> 3; b = r >> 4; by = r & 15; }
  else { const int w = id - 512; bx = 8 + (w >> 6); const int r = w & 63; b = r >> 4; by = r & 15; }
  const int cnt = kcount[b];
  if (bx * 128 >= cnt) return;          // dead key-tile

  f32x16 acc[2][2];
  const size_t qoff = ((size_t)b * S_LEN + by * 128) * HDIM;
  const size_t koff = ((size_t)b * S_LEN + bx * 128) * HDIM;
  gemm_core_split(lds, qhi + qoff, qlo + qoff, khi + koff, klo + koff,
                  HDIM, HDIM, HDIM, acc);
  const int lane = threadIdx.x & 63, wave = threadIdx.x >> 6;
  const int wm = wave >> 1, wn = wave & 1;
#pragma unroll
  for (int i = 0; i < 2; ++i) {
#pragma unroll
    for (int j = 0; j < 2; ++j) {
#pragma unroll
      for (int rr = 0; rr < 16; ++rr) {
        const int q   = by * 128 + wm * 64 + i * 32 + ROW32(rr, lane);
        const int key = bx * 128 + wn * 64 + j * 32 + (lane & 31);     // compact
        scores[((size_t)b * S_LEN + q) * S_LEN + key] = 32.0f * acc[i][j][rr];
      }
    }
  }
}

// ---------- softmax: one wave per row, cnt-masked, in-place fp32 -> bf16 ----------
__global__ __launch_bounds__(256) void softmax_kernel(
    float* __restrict__ scores, const int* __restrict__ kcount) {
  const int wave = threadIdx.x >> 6, lane = threadIdx.x & 63;
  const int row = blockIdx.x * 4 + wave;
  const int b = row >> 11;
  const int cnt = kcount[b];
  const int nc = (cnt + 255) >> 8;     // active 256-col chunks
  float* srow = scores + (size_t)row * S_LEN;
  const float ninf = -__builtin_inff();

  f32x4 v[8];
  float m = ninf;
#pragma unroll
  for (int c = 0; c < 8; ++c) {
    if (c < nc) {
      v[c] = ((const f32x4*)srow)[c * 64 + lane];
      const int j0 = c * 256 + lane * 4;
#pragma unroll
      for (int e = 0; e < 4; ++e) {
        if (j0 + e >= cnt) v[c][e] = ninf;   // pad/garbage -> masked
        m = fmaxf(m, v[c][e]);
      }
    }
  }
#pragma unroll
  for (int o = 32; o > 0; o >>= 1) m = fmaxf(m, __shfl_xor(m, o));

  float s = 0.f;
#pragma unroll
  for (int c = 0; c < 8; ++c) {
    if (c < nc) {
#pragma unroll
      for (int e = 0; e < 4; ++e) {
        v[c][e] = __expf(v[c][e] - m);       // exp(-inf - m) = 0
        s += v[c][e];
      }
    }
  }
#pragma unroll
  for (int o = 32; o > 0; o >>= 1) s += __shfl_xor(s, o);
  const float inv = 1.0f / s;

  u16* prow = (u16*)srow;   // bf16 row at same base; stride 4096 u16
#pragma unroll
  for (int c = 0; c < 8; ++c) {
    if (c < nc) {
      u16x4 o4 = { f2bf(v[c][0] * inv), f2bf(v[c][1] * inv),
                   f2bf(v[c][2] * inv), f2bf(v[c][3] * inv) };
      ((u16x4*)prow)[c * 64 + lane] = o4;
    }
  }
}

// ---------- PV GEMM: out = P @ Vt^T, K = ceil64(cnt) ----------
// XCD-aware decode (Vt stripes pinned per XCD); 32KB LDS -> (256,4).
__global__ __launch_bounds__(256, 4) void pv_kernel(
    const u16* __restrict__ P, const u16* __restrict__ vt,
    const int* __restrict__ kcount, float* __restrict__ out)
{
  __shared__ __align__(16) u16 lds[2 * 8192];
  const int id   = blockIdx.x;          // 0..511
  const int xcd  = id & 7;
  const int s    = id >> 3;             // 0..63
  const int b    = s >> 4;              // batch 0..3
  const int slot = s & 15;
  const int bx   = (xcd & 1) * 4 + (slot & 3);   // H-tile 0..7
  const int by   = (xcd >> 1) * 4 + (slot >> 2); // Q-tile 0..15
  const int cnt  = kcount[b];
  const int K    = (cnt + 63) & ~63;    // P zero on [cnt,K); Vt finite there

  f32x16 acc[2][2];
  gemm_core_plain(lds,
                  P + ((size_t)b * S_LEN + by * 128) * (2 * S_LEN),
                  vt + ((size_t)b * HDIM + bx * 128) * S_LEN,
                  2 * S_LEN, S_LEN, K, acc);
  const int lane = threadIdx.x & 63, wave = threadIdx.x >> 6;
  const int wm = wave >> 1, wn = wave & 1;
#pragma unroll
  for (int i = 0; i < 2; ++i) {
#pragma unroll
    for (int j = 0; j < 2; ++j) {
#pragma unroll
      for (int r = 0; r < 16; ++r) {
        const int q = by * 128 + wm * 64 + i * 32 + ROW32(r, lane);
        const int h = bx * 128 + wn * 64 + j * 32 + (lane & 31);
        out[((size_t)b * S_LEN + q) * HDIM + h] = acc[i][j][r];
      }
    }
  }
}

extern "C" void kernel_launch(void* const* d_in, const int* in_sizes, int n_in,
                              void* d_out, int out_size, void* d_ws, size_t ws_size,
                              hipStream_t stream)
{
  const float* qkv  = (const float*)d_in[0];
  const void*  mask = d_in[1];
  const float* W    = (const float*)d_in[2];
  const float* bias = (const float*)d_in[3];
  float* out = (float*)d_out;
  char* ws = (char*)d_ws;

  const size_t off_cnt  = 0;                         // 4 ints
  const size_t off_idx  = 256;                       // 4*2048*4 = 32 KiB
  const size_t off_Whi  = 33024;                     // 128-aligned
  const size_t off_Wlo  = off_Whi + (size_t)N3H * DIN * 2;
  const size_t off_Qhi  = off_Wlo + (size_t)N3H * DIN * 2;
  const size_t off_Qlo  = off_Qhi + (size_t)NTOK * HDIM * 2;
  const size_t off_Khi  = off_Qlo + (size_t)NTOK * HDIM * 2;
  const size_t off_Klo  = off_Khi + (size_t)NTOK * HDIM * 2;
  const size_t off_Vt   = off_Klo + (size_t)NTOK * HDIM * 2;
  const size_t off_A    = off_Vt + (size_t)NTOK * HDIM * 2;
  const size_t off_Alo  = off_A + (size_t)NTOK * DIN * 2;
  const size_t off_sc   = off_A;  // scores (67MB) overlay A-split (dead after proj)
  // total ws requirement: off_A + BATCH*S*S*4 = ~156 MiB (same as before)

  int* kcount = (int*)(ws + off_cnt);
  int* idx    = (int*)(ws + off_idx);
  u16* Whi = (u16*)(ws + off_Whi);  u16* Wlo = (u16*)(ws + off_Wlo);
  u16* Qhi = (u16*)(ws + off_Qhi);  u16* Qlo = (u16*)(ws + off_Qlo);
  u16* Khi = (u16*)(ws + off_Khi);  u16* Klo = (u16*)(ws + off_Klo);
  u16* Vt  = (u16*)(ws + off_Vt);
  u16* Ahi = (u16*)(ws + off_A);    u16* Alo = (u16*)(ws + off_Alo);
  float* scores = (float*)(ws + off_sc);

  front_kernel<<<11265, 256, 0, stream>>>(
      qkv, W, (const unsigned char*)mask, Ahi, Alo, Whi, Wlo, idx, kcount);
  proj_q_kernel<<<dim3(HDIM / 128, NTOK / 128), 256, 0, stream>>>(
      Ahi, Alo, Whi, Wlo, bias, Qhi, Qlo);
  proj_k_kernel<<<512, 256, 0, stream>>>(
      Ahi, Alo, Whi, Wlo, bias, idx, kcount, Khi, Klo);
  proj_v_kernel<<<512, 256, 0, stream>>>(
      Ahi, Whi, bias, idx, kcount, Vt);
  scores_kernel<<<1024, 256, 0, stream>>>(
      Qhi, Qlo, Khi, Klo, kcount, scores);
  softmax_kernel<<<NTOK / 4, 256, 0, stream>>>(scores, kcount);
  pv_kernel<<<8 * 16 * BATCH, 256, 0, stream>>>(
      (const u16*)scores, Vt, kcount, out);
}

// Round 11
// 353.609 us; speedup vs baseline: 1.0845x; 1.0845x over previous
//
#include <hip/hip_runtime.h>
#include <stdint.h>

// Problem: B=4, S=2048, D_IN=1024, H=1024; fp32 in/out.
// R15: 128^2 core + mask compaction (key mask kills whole columns). 414->382.
// R16: scores live-prefix decode (bx slow-major: 64 consecutive blocks share
//      a K-tile -> L2). 382->370.7. BEST MEASURED.
// R17: heterogeneous proj merge FAILED (26.6% MfmaUtil). scores-XCD claim
//      was never actually measured.
// R18: front-merge + (256,4) + scores bx=id&7 ALL regressed (383.5; scores
//      FETCH 88->145MB -- id&7 destroys consecutive-block K-tile sharing).
// R19: revert to R16 wholesale + ONE change: merge proj_q+proj_k into one
//      HOMOGENEOUS split-core launch (R17 failed with mixed core types; Q and
//      K share the identical split core + 64KB LDS; only staging addressing
//      differs). 768 live blocks = 3/CU with backfill = R0's 40%-regime
//      (R0 fused proj_qk: 1024 blocks, 111us @ 40%; the R15 split put Q,K in
//      the starved one-shot ~26% regime costing ~120us total).
//      Decode: ids 0..767 in groups of 3 = {Q,Q,K}; ids 768..1023 = K tails
//      (t=8..15, live iff cnt>1024). Single 64KB LDS buffer passed to cores.

#define S_LEN 2048
#define BATCH 4
#define DIN   1024
#define HDIM  1024
#define N3H   3072
#define NTOK  8192   // BATCH*S_LEN

typedef unsigned short u16;
typedef __attribute__((ext_vector_type(8))) short bf16x8;
typedef __attribute__((ext_vector_type(4))) float f32x4;
typedef __attribute__((ext_vector_type(16))) float f32x16;
typedef __attribute__((ext_vector_type(4))) unsigned short u16x4;

// ---------- bf16 helpers (bit ops, RN) ----------
__device__ __forceinline__ u16 f2bf(float x) {
  union { float f; unsigned u; } c; c.f = x;
  unsigned r = c.u + 0x7fffu + ((c.u >> 16) & 1u);
  return (u16)(r >> 16);
}
__device__ __forceinline__ float bf2f(u16 h) {
  union { unsigned u; float f; } c; c.u = ((unsigned)h) << 16;
  return c.f;
}

// ---------- async global->LDS, width 16 ----------
__device__ __forceinline__ void gload16(const void* g, void* lds) {
  auto* gp = reinterpret_cast<const __attribute__((address_space(1))) void*>(
      reinterpret_cast<uintptr_t>(g));
  auto* lp = reinterpret_cast<__attribute__((address_space(3))) void*>(
      (unsigned)reinterpret_cast<uintptr_t>(lds));
  __builtin_amdgcn_global_load_lds(gp, lp, 16, 0, 0);
}

// Stage a 128x64 bf16 tile (row-major, row stride ld elems) into swizzled LDS.
// Layout: element (row, kb=k/8) at byte row*128 + ((kb ^ (row&7))*16).
__device__ __forceinline__ void stage_tile(const u16* __restrict__ g, int ld,
                                           u16* lds, int wave, int lane) {
  const int rlane = lane >> 3;                       // 0..7: row within instr
  const int kb    = (lane & 7) ^ (rlane & 7);        // swizzled k-block
#pragma unroll
  for (int h = 0; h < 4; ++h) {
    const int instr = wave * 4 + h;                  // 0..15
    const u16* gp = g + (size_t)(instr * 8 + rlane) * ld + kb * 8;
    gload16(gp, (char*)lds + instr * 1024);
  }
}

// Indirect-row variant: rows come from idxb[jbase + r] (compact -> token).
__device__ __forceinline__ void stage_tile_idx(
    const u16* __restrict__ gbase, const int* __restrict__ idxb, int jbase,
    int k0, u16* lds, int wave, int lane) {
  const int rlane = lane >> 3;
  const int kb    = (lane & 7) ^ (rlane & 7);
#pragma unroll
  for (int h = 0; h < 4; ++h) {
    const int instr = wave * 4 + h;
    const int s = idxb[jbase + instr * 8 + rlane];   // original token row
    const u16* gp = gbase + (size_t)s * DIN + k0 + kb * 8;
    gload16(gp, (char*)lds + instr * 1024);
  }
}

// 32x32x16 fragment fetch from swizzled [128][64] LDS tile.
// A-operand layout: A[m=lane&31][k=(lane>>5)*8+j] (R5/R6-verified).
__device__ __forceinline__ bf16x8 frag32(const u16* t, int wq, int sub, int kh,
                                         int lane) {
  const int r5   = lane & 31;
  const int row  = wq * 64 + sub * 32 + r5;
  const int slot = (kh * 2 + (lane >> 5)) ^ (r5 & 7);
  return *(const bf16x8*)(t + row * 64 + slot * 8);
}

// ---------- split-precision gemm_bt core: C(128x128) += (Ah+Al)*(Bh+Bl)^T ----------
// lds: 64KB (4 x 16KB regions) provided by the caller.
__device__ __forceinline__ void gemm_core_split(
    u16* lds,
    const u16* __restrict__ Ah, const u16* __restrict__ Al,
    const u16* __restrict__ Bh, const u16* __restrict__ Bl,
    int lda, int ldb, int K, f32x16 acc[2][2])
{
  u16* aH = lds;           u16* aL = lds + 8192;
  u16* bH = lds + 16384;   u16* bL = lds + 24576;
  const int tid  = threadIdx.x;
  const int wave = tid >> 6, lane = tid & 63;
  const int wm = wave >> 1, wn = wave & 1;

#pragma unroll
  for (int i = 0; i < 2; ++i)
#pragma unroll
    for (int j = 0; j < 2; ++j)
#pragma unroll
      for (int r = 0; r < 16; ++r) acc[i][j][r] = 0.f;

  for (int k0 = 0; k0 < K; k0 += 64) {
    stage_tile(Ah + k0, lda, aH, wave, lane);
    stage_tile(Al + k0, lda, aL, wave, lane);
    stage_tile(Bh + k0, ldb, bH, wave, lane);
    stage_tile(Bl + k0, ldb, bL, wave, lane);
    __syncthreads();   // drains vmcnt (global_load_lds) before LDS reads

#pragma unroll
    for (int kh = 0; kh < 4; ++kh) {
      bf16x8 fah[2], fal[2];
#pragma unroll
      for (int i = 0; i < 2; ++i) {
        fah[i] = frag32(aH, wm, i, kh, lane);
        fal[i] = frag32(aL, wm, i, kh, lane);
      }
#pragma unroll
      for (int j = 0; j < 2; ++j) {
        const bf16x8 fbh = frag32(bH, wn, j, kh, lane);
        const bf16x8 fbl = frag32(bL, wn, j, kh, lane);
#pragma unroll
        for (int i = 0; i < 2; ++i) {
          acc[i][j] = __builtin_amdgcn_mfma_f32_32x32x16_bf16(fah[i], fbh, acc[i][j], 0, 0, 0);
          acc[i][j] = __builtin_amdgcn_mfma_f32_32x32x16_bf16(fah[i], fbl, acc[i][j], 0, 0, 0);
          acc[i][j] = __builtin_amdgcn_mfma_f32_32x32x16_bf16(fal[i], fbh, acc[i][j], 0, 0, 0);
        }
      }
    }
    __syncthreads();   // protect LDS before next stage
  }
}

// Same core, A rows fetched through idx (compact rows jbase..jbase+127).
__device__ __forceinline__ void gemm_core_split_idx(
    u16* lds,
    const u16* __restrict__ Ah, const u16* __restrict__ Al,  // batch base
    const int* __restrict__ idxb, int jbase,
    const u16* __restrict__ Bh, const u16* __restrict__ Bl,
    f32x16 acc[2][2])
{
  u16* aH = lds;           u16* aL = lds + 8192;
  u16* bH = lds + 16384;   u16* bL = lds + 24576;
  const int tid  = threadIdx.x;
  const int wave = tid >> 6, lane = tid & 63;
  const int wm = wave >> 1, wn = wave & 1;

#pragma unroll
  for (int i = 0; i < 2; ++i)
#pragma unroll
    for (int j = 0; j < 2; ++j)
#pragma unroll
      for (int r = 0; r < 16; ++r) acc[i][j][r] = 0.f;

  for (int k0 = 0; k0 < DIN; k0 += 64) {
    stage_tile_idx(Ah, idxb, jbase, k0, aH, wave, lane);
    stage_tile_idx(Al, idxb, jbase, k0, aL, wave, lane);
    stage_tile(Bh + k0, DIN, bH, wave, lane);
    stage_tile(Bl + k0, DIN, bL, wave, lane);
    __syncthreads();

#pragma unroll
    for (int kh = 0; kh < 4; ++kh) {
      bf16x8 fah[2], fal[2];
#pragma unroll
      for (int i = 0; i < 2; ++i) {
        fah[i] = frag32(aH, wm, i, kh, lane);
        fal[i] = frag32(aL, wm, i, kh, lane);
      }
#pragma unroll
      for (int j = 0; j < 2; ++j) {
        const bf16x8 fbh = frag32(bH, wn, j, kh, lane);
        const bf16x8 fbl = frag32(bL, wn, j, kh, lane);
#pragma unroll
        for (int i = 0; i < 2; ++i) {
          acc[i][j] = __builtin_amdgcn_mfma_f32_32x32x16_bf16(fah[i], fbh, acc[i][j], 0, 0, 0);
          acc[i][j] = __builtin_amdgcn_mfma_f32_32x32x16_bf16(fah[i], fbl, acc[i][j], 0, 0, 0);
          acc[i][j] = __builtin_amdgcn_mfma_f32_32x32x16_bf16(fal[i], fbh, acc[i][j], 0, 0, 0);
        }
      }
    }
    __syncthreads();
  }
}

// ---------- plain bf16 gemm_bt core (lds: 32KB) ----------
__device__ __forceinline__ void gemm_core_plain(
    u16* lds,
    const u16* __restrict__ A, const u16* __restrict__ B,
    int lda, int ldb, int K, f32x16 acc[2][2])
{
  u16* aT = lds; u16* bT = lds + 8192;
  const int tid  = threadIdx.x;
  const int wave = tid >> 6, lane = tid & 63;
  const int wm = wave >> 1, wn = wave & 1;

#pragma unroll
  for (int i = 0; i < 2; ++i)
#pragma unroll
    for (int j = 0; j < 2; ++j)
#pragma unroll
      for (int r = 0; r < 16; ++r) acc[i][j][r] = 0.f;

  for (int k0 = 0; k0 < K; k0 += 64) {
    stage_tile(A + k0, lda, aT, wave, lane);
    stage_tile(B + k0, ldb, bT, wave, lane);
    __syncthreads();
#pragma unroll
    for (int kh = 0; kh < 4; ++kh) {
      bf16x8 fa[2];
#pragma unroll
      for (int i = 0; i < 2; ++i) fa[i] = frag32(aT, wm, i, kh, lane);
#pragma unroll
      for (int j = 0; j < 2; ++j) {
        const bf16x8 fb = frag32(bT, wn, j, kh, lane);
#pragma unroll
        for (int i = 0; i < 2; ++i)
          acc[i][j] = __builtin_amdgcn_mfma_f32_32x32x16_bf16(fa[i], fb, acc[i][j], 0, 0, 0);
      }
    }
    __syncthreads();
  }
}

// Plain core, A rows via idx (for proj V), lda = DIN implicit.
__device__ __forceinline__ void gemm_core_plain_idx(
    u16* lds,
    const u16* __restrict__ A, const int* __restrict__ idxb, int jbase,
    const u16* __restrict__ B, f32x16 acc[2][2])
{
  u16* aT = lds; u16* bT = lds + 8192;
  const int tid  = threadIdx.x;
  const int wave = tid >> 6, lane = tid & 63;
  const int wm = wave >> 1, wn = wave & 1;

#pragma unroll
  for (int i = 0; i < 2; ++i)
#pragma unroll
    for (int j = 0; j < 2; ++j)
#pragma unroll
      for (int r = 0; r < 16; ++r) acc[i][j][r] = 0.f;

  for (int k0 = 0; k0 < DIN; k0 += 64) {
    stage_tile_idx(A, idxb, jbase, k0, aT, wave, lane);
    stage_tile(B + k0, DIN, bT, wave, lane);
    __syncthreads();
#pragma unroll
    for (int kh = 0; kh < 4; ++kh) {
      bf16x8 fa[2];
#pragma unroll
      for (int i = 0; i < 2; ++i) fa[i] = frag32(aT, wm, i, kh, lane);
#pragma unroll
      for (int j = 0; j < 2; ++j) {
        const bf16x8 fb = frag32(bT, wn, j, kh, lane);
#pragma unroll
        for (int i = 0; i < 2; ++i)
          acc[i][j] = __builtin_amdgcn_mfma_f32_32x32x16_bf16(fa[i], fb, acc[i][j], 0, 0, 0);
      }
    }
    __syncthreads();
  }
}

// C/D layout for 32x32 (HW-verified m74/m101):
//   col = lane&31, row = (reg&3) + 8*(reg>>2) + 4*(lane>>5)
#define ROW32(r, lane) (((r) & 3) + 8 * ((r) >> 2) + 4 * ((lane) >> 5))

// ---------- prep: repr-detect + per-batch compaction scan ----------
// idx[b][j] = token index of j-th UNMASKED key (j < kcount[b]); 0 beyond.
__global__ void prep_kernel(const unsigned char* __restrict__ m,
                            int* __restrict__ idx, int* __restrict__ kcount) {
  __shared__ int isBool;
  if (threadIdx.x == 0) isBool = 0;
  __syncthreads();
  for (int i = threadIdx.x; i < NTOK; i += 256)
    if ((i & 3) && m[i]) isBool = 1;   // int32 repr of 0/1 has zero bytes at %4!=0
  __syncthreads();
  const int stride = isBool ? 1 : 4;
  const int wave = threadIdx.x >> 6, lane = threadIdx.x & 63;
  const int b = wave;                  // 4 waves, one batch each
  const int base = b * S_LEN;
  int running = 0;
#pragma unroll 1
  for (int c = 0; c < S_LEN / 64; ++c) {
    const int s = c * 64 + lane;
    const int um = (m[(size_t)(base + s) * stride] == 0);   // unmasked key
    const unsigned long long bal = __ballot(um);
    const int pre = (int)__popcll(bal & ((1ULL << lane) - 1ULL));
    if (um) idx[base + running + pre] = s;
    running += (int)__popcll(bal);     // wave-uniform
  }
  if (lane == 0) kcount[b] = running;
  for (int j = running + lane; j < S_LEN; j += 64) idx[base + j] = 0;
}

// ---------- split fp32 -> bf16 hi/lo ----------
__global__ __launch_bounds__(256) void split_f32_kernel(
    const float* __restrict__ x, u16* __restrict__ hi, u16* __restrict__ lo) {
  const int i = (blockIdx.x * 256 + threadIdx.x) * 4;
  const f32x4 v = *(const f32x4*)(x + i);
  u16x4 h, l;
#pragma unroll
  for (int c = 0; c < 4; ++c) {
    h[c] = f2bf(v[c]);
    l[c] = f2bf(v[c] - bf2f(h[c]));
  }
  *(u16x4*)(hi + i) = h;
  *(u16x4*)(lo + i) = l;
}

// ---------- transpose + split W (DINxN3H -> N3HxDIN), 32x32 LDS tile ----------
__global__ __launch_bounds__(256) void splitWT_kernel(
    const float* __restrict__ W, u16* __restrict__ whi, u16* __restrict__ wlo) {
  __shared__ float tile[32][33];
  const int t = threadIdx.x;
  const int n0 = blockIdx.x * 32;   // 96 tiles over N3H
  const int d0 = blockIdx.y * 32;   // 32 tiles over DIN
  const int dr = t >> 3, nc = (t & 7) * 4;
  const f32x4 v = *(const f32x4*)(W + (size_t)(d0 + dr) * N3H + n0 + nc);
#pragma unroll
  for (int c = 0; c < 4; ++c) tile[dr][nc + c] = v[c];
  __syncthreads();
  const int nr = t >> 3, dc = (t & 7) * 4;
  u16x4 h, l;
#pragma unroll
  for (int c = 0; c < 4; ++c) {
    const float x = tile[dc + c][nr];
    h[c] = f2bf(x);
    l[c] = f2bf(x - bf2f(h[c]));
  }
  const size_t o = (size_t)(n0 + nr) * DIN + d0 + dc;
  *(u16x4*)(whi + o) = h;
  *(u16x4*)(wlo + o) = l;
}

// ---------- merged projection Q+K: ONE homogeneous split-core launch ----------
// ids 0..767: groups of 3 = {Q, Q, K} -> 512 Q-blocks + 256 K-blocks, all
// live (cnt<=1024 typical) = 3 blocks/CU with backfill (R0's 40% regime).
// ids 768..1023: K tails t=8..15, live iff cnt > 1024. Both paths use the
// IDENTICAL split core + 64KB LDS; only staging addressing differs (direct
// rows for Q, idx rows for K) -- homogeneous, unlike R17's failed 3-type mix.
__global__ __launch_bounds__(256, 2) void proj_qk_kernel(
    const u16* __restrict__ Ahi, const u16* __restrict__ Alo,
    const u16* __restrict__ Whi, const u16* __restrict__ Wlo,
    const float* __restrict__ bias,
    const int* __restrict__ idx, const int* __restrict__ kcount,
    u16* __restrict__ qhi, u16* __restrict__ qlo,
    u16* __restrict__ khi, u16* __restrict__ klo)
{
  __shared__ __align__(16) u16 lds[4 * 8192];   // 64 KiB
  const int id = blockIdx.x;            // 0..1023
  bool isQ = false;
  int q = 0, t = 0, b = 0, bx = 0;
  if (id < 768) {
    const int g = id / 3, l = id - g * 3;
    if (l < 2) { isQ = true; q = g * 2 + l; }              // 0..511
    else       { t = g >> 5; const int rs = g & 31; b = rs >> 3; bx = rs & 7; }
  } else {
    const int k = 256 + (id - 768);     // 256..511 -> t=8..15
    t = k >> 5; const int rs = k & 31; b = rs >> 3; bx = rs & 7;
  }
  if (!isQ && t * 128 >= kcount[b]) return;   // dead K tile

  const int lane = threadIdx.x & 63, wave = threadIdx.x >> 6;
  const int wm = wave >> 1, wn = wave & 1;
  f32x16 acc[2][2];

  if (isQ) {                    // ---- Q: split, full rows ----
    const int qbx = q & 7, qby = q >> 3;
    gemm_core_split(lds,
                    Ahi + (size_t)qby * 128 * DIN, Alo + (size_t)qby * 128 * DIN,
                    Whi + (size_t)qbx * 128 * DIN, Wlo + (size_t)qbx * 128 * DIN,
                    DIN, DIN, DIN, acc);
#pragma unroll
    for (int i = 0; i < 2; ++i) {
#pragma unroll
      for (int j = 0; j < 2; ++j) {
#pragma unroll
        for (int r = 0; r < 16; ++r) {
          const int row = qby * 128 + wm * 64 + i * 32 + ROW32(r, lane);
          const int col = qbx * 128 + wn * 64 + j * 32 + (lane & 31);
          const float v = acc[i][j][r] + bias[col];
          const u16 h = f2bf(v);
          const u16 l = f2bf(v - bf2f(h));
          const size_t o = (size_t)row * HDIM + col;
          qhi[o] = h; qlo[o] = l;
        }
      }
    }
  } else {                      // ---- K: split, compacted rows ----
    gemm_core_split_idx(lds,
                        Ahi + (size_t)b * S_LEN * DIN, Alo + (size_t)b * S_LEN * DIN,
                        idx + b * S_LEN, t * 128,
                        Whi + (size_t)(HDIM + bx * 128) * DIN,
                        Wlo + (size_t)(HDIM + bx * 128) * DIN, acc);
#pragma unroll
    for (int i = 0; i < 2; ++i) {
#pragma unroll
      for (int j = 0; j < 2; ++j) {
#pragma unroll
        for (int r = 0; r < 16; ++r) {
          const int jl   = t * 128 + wm * 64 + i * 32 + ROW32(r, lane);
          const int hcol = bx * 128 + wn * 64 + j * 32 + (lane & 31);
          const float v = acc[i][j][r] + bias[HDIM + hcol];
          const u16 h = f2bf(v);
          const u16 l = f2bf(v - bf2f(h));
          const size_t o = ((size_t)b * S_LEN + jl) * HDIM + hcol;
          khi[o] = h; klo[o] = l;
        }
      }
    }
  }
}

// ---------- projection GEMM (V third): plain bf16, compacted, V transposed ----------
__global__ __launch_bounds__(256, 2) void proj_v_kernel(
    const u16* __restrict__ Ahi, const u16* __restrict__ Whi,
    const float* __restrict__ bias,
    const int* __restrict__ idx, const int* __restrict__ kcount,
    u16* __restrict__ vt)
{
  __shared__ __align__(16) u16 lds[2 * 8192];
  const int id = blockIdx.x;           // 0..511
  const int t  = id >> 5;
  const int rs = id & 31;
  const int b  = rs >> 3;
  const int bx = rs & 7;               // H-col tile
  const int cnt = kcount[b];
  if (t * 128 >= cnt) return;

  f32x16 acc[2][2];
  gemm_core_plain_idx(lds,
                      Ahi + (size_t)b * S_LEN * DIN, idx + b * S_LEN, t * 128,
                      Whi + (size_t)(2048 + bx * 128) * DIN, acc);
  const int lane = threadIdx.x & 63, wave = threadIdx.x >> 6;
  const int wm = wave >> 1, wn = wave & 1;
#pragma unroll
  for (int i = 0; i < 2; ++i) {
#pragma unroll
    for (int j = 0; j < 2; ++j) {
#pragma unroll
      for (int r = 0; r < 16; ++r) {
        const int jl   = t * 128 + wm * 64 + i * 32 + ROW32(r, lane);  // compact col
        const int hcol = bx * 128 + wn * 64 + j * 32 + (lane & 31);
        const float v = acc[i][j][r] + bias[2 * HDIM + hcol];
        vt[((size_t)b * HDIM + hcol) * S_LEN + jl] = f2bf(v);
      }
    }
  }
}

// ---------- scores GEMM: sc = 32 * Q @ Kc^T (compact keys) ----------
// R16 decode (BEST measured: 82.6us, FETCH 88MB): bx SLOW-major -> live ids
// form a dispatch-order prefix AND 64 consecutive blocks share one K-tile
// (L2-friendly). ids with bx*128>=cnt retire immediately.
__global__ __launch_bounds__(256, 2) void scores_kernel(
    const u16* __restrict__ qhi, const u16* __restrict__ qlo,
    const u16* __restrict__ khi, const u16* __restrict__ klo,
    const int* __restrict__ kcount, float* __restrict__ scores)
{
  __shared__ __align__(16) u16 lds[4 * 8192];
  const int id = blockIdx.x;            // 0..1023
  const int bx = id >> 6;               // key-tile 0..15 (slowest)
  const int b  = (id >> 4) & 3;         // batch
  const int by = id & 15;               // Q-tile
  const int cnt = kcount[b];
  if (bx * 128 >= cnt) return;          // dead key-tile (prefix property)

  f32x16 acc[2][2];
  const size_t qoff = ((size_t)b * S_LEN + by * 128) * HDIM;
  const size_t koff = ((size_t)b * S_LEN + bx * 128) * HDIM;
  gemm_core_split(lds, qhi + qoff, qlo + qoff, khi + koff, klo + koff,
                  HDIM, HDIM, HDIM, acc);
  const int lane = threadIdx.x & 63, wave = threadIdx.x >> 6;
  const int wm = wave >> 1, wn = wave & 1;
#pragma unroll
  for (int i = 0; i < 2; ++i) {
#pragma unroll
    for (int j = 0; j < 2; ++j) {
#pragma unroll
      for (int rr = 0; rr < 16; ++rr) {
        const int q   = by * 128 + wm * 64 + i * 32 + ROW32(rr, lane);
        const int key = bx * 128 + wn * 64 + j * 32 + (lane & 31);     // compact
        scores[((size_t)b * S_LEN + q) * S_LEN + key] = 32.0f * acc[i][j][rr];
      }
    }
  }
}

// ---------- softmax: one wave per row, cnt-masked, in-place fp32 -> bf16 ----------
__global__ __launch_bounds__(256) void softmax_kernel(
    float* __restrict__ scores, const int* __restrict__ kcount) {
  const int wave = threadIdx.x >> 6, lane = threadIdx.x & 63;
  const int row = blockIdx.x * 4 + wave;
  const int b = row >> 11;
  const int cnt = kcount[b];
  const int nc = (cnt + 255) >> 8;     // active 256-col chunks
  float* srow = scores + (size_t)row * S_LEN;
  const float ninf = -__builtin_inff();

  f32x4 v[8];
  float m = ninf;
#pragma unroll
  for (int c = 0; c < 8; ++c) {
    if (c < nc) {
      v[c] = ((const f32x4*)srow)[c * 64 + lane];
      const int j0 = c * 256 + lane * 4;
#pragma unroll
      for (int e = 0; e < 4; ++e) {
        if (j0 + e >= cnt) v[c][e] = ninf;   // pad/garbage -> masked
        m = fmaxf(m, v[c][e]);
      }
    }
  }
#pragma unroll
  for (int o = 32; o > 0; o >>= 1) m = fmaxf(m, __shfl_xor(m, o));

  float s = 0.f;
#pragma unroll
  for (int c = 0; c < 8; ++c) {
    if (c < nc) {
#pragma unroll
      for (int e = 0; e < 4; ++e) {
        v[c][e] = __expf(v[c][e] - m);       // exp(-inf - m) = 0
        s += v[c][e];
      }
    }
  }
#pragma unroll
  for (int o = 32; o > 0; o >>= 1) s += __shfl_xor(s, o);
  const float inv = 1.0f / s;

  u16* prow = (u16*)srow;   // bf16 row at same base; stride 4096 u16
#pragma unroll
  for (int c = 0; c < 8; ++c) {
    if (c < nc) {
      u16x4 o4 = { f2bf(v[c][0] * inv), f2bf(v[c][1] * inv),
                   f2bf(v[c][2] * inv), f2bf(v[c][3] * inv) };
      ((u16x4*)prow)[c * 64 + lane] = o4;
    }
  }
}

// ---------- PV GEMM: out = P @ Vt^T, K = ceil64(cnt) ----------
// XCD-aware decode (Vt stripes pinned per XCD).
__global__ __launch_bounds__(256, 2) void pv_kernel(
    const u16* __restrict__ P, const u16* __restrict__ vt,
    const int* __restrict__ kcount, float* __restrict__ out)
{
  __shared__ __align__(16) u16 lds[2 * 8192];
  const int id   = blockIdx.x;          // 0..511
  const int xcd  = id & 7;
  const int s    = id >> 3;             // 0..63
  const int b    = s >> 4;              // batch 0..3
  const int slot = s & 15;
  const int bx   = (xcd & 1) * 4 + (slot & 3);   // H-tile 0..7
  const int by   = (xcd >> 1) * 4 + (slot >> 2); // Q-tile 0..15
  const int cnt  = kcount[b];
  const int K    = (cnt + 63) & ~63;    // P zero on [cnt,K); Vt finite there

  f32x16 acc[2][2];
  gemm_core_plain(lds,
                  P + ((size_t)b * S_LEN + by * 128) * (2 * S_LEN),
                  vt + ((size_t)b * HDIM + bx * 128) * S_LEN,
                  2 * S_LEN, S_LEN, K, acc);
  const int lane = threadIdx.x & 63, wave = threadIdx.x >> 6;
  const int wm = wave >> 1, wn = wave & 1;
#pragma unroll
  for (int i = 0; i < 2; ++i) {
#pragma unroll
    for (int j = 0; j < 2; ++j) {
#pragma unroll
      for (int r = 0; r < 16; ++r) {
        const int q = by * 128 + wm * 64 + i * 32 + ROW32(r, lane);
        const int h = bx * 128 + wn * 64 + j * 32 + (lane & 31);
        out[((size_t)b * S_LEN + q) * HDIM + h] = acc[i][j][r];
      }
    }
  }
}

extern "C" void kernel_launch(void* const* d_in, const int* in_sizes, int n_in,
                              void* d_out, int out_size, void* d_ws, size_t ws_size,
                              hipStream_t stream)
{
  const float* qkv  = (const float*)d_in[0];
  const void*  mask = d_in[1];
  const float* W    = (const float*)d_in[2];
  const float* bias = (const float*)d_in[3];
  float* out = (float*)d_out;
  char* ws = (char*)d_ws;

  const size_t off_cnt  = 0;                         // 4 ints
  const size_t off_idx  = 256;                       // 4*2048*4 = 32 KiB
  const size_t off_Whi  = 33024;                     // 128-aligned
  const size_t off_Wlo  = off_Whi + (size_t)N3H * DIN * 2;
  const size_t off_Qhi  = off_Wlo + (size_t)N3H * DIN * 2;
  const size_t off_Qlo  = off_Qhi + (size_t)NTOK * HDIM * 2;
  const size_t off_Khi  = off_Qlo + (size_t)NTOK * HDIM * 2;
  const size_t off_Klo  = off_Khi + (size_t)NTOK * HDIM * 2;
  const size_t off_Vt   = off_Klo + (size_t)NTOK * HDIM * 2;
  const size_t off_A    = off_Vt + (size_t)NTOK * HDIM * 2;
  const size_t off_Alo  = off_A + (size_t)NTOK * DIN * 2;
  const size_t off_sc   = off_A;  // scores (67MB) overlay A-split (dead after proj)
  // total ws requirement: off_A + BATCH*S*S*4 = ~156 MiB (same as before)

  int* kcount = (int*)(ws + off_cnt);
  int* idx    = (int*)(ws + off_idx);
  u16* Whi = (u16*)(ws + off_Whi);  u16* Wlo = (u16*)(ws + off_Wlo);
  u16* Qhi = (u16*)(ws + off_Qhi);  u16* Qlo = (u16*)(ws + off_Qlo);
  u16* Khi = (u16*)(ws + off_Khi);  u16* Klo = (u16*)(ws + off_Klo);
  u16* Vt  = (u16*)(ws + off_Vt);
  u16* Ahi = (u16*)(ws + off_A);    u16* Alo = (u16*)(ws + off_Alo);
  float* scores = (float*)(ws + off_sc);

  prep_kernel<<<1, 256, 0, stream>>>((const unsigned char*)mask, idx, kcount);
  split_f32_kernel<<<NTOK * DIN / 1024, 256, 0, stream>>>(qkv, Ahi, Alo);
  splitWT_kernel<<<dim3(N3H / 32, DIN / 32), 256, 0, stream>>>(W, Whi, Wlo);
  proj_qk_kernel<<<1024, 256, 0, stream>>>(
      Ahi, Alo, Whi, Wlo, bias, idx, kcount, Qhi, Qlo, Khi, Klo);
  proj_v_kernel<<<512, 256, 0, stream>>>(
      Ahi, Whi, bias, idx, kcount, Vt);
  scores_kernel<<<1024, 256, 0, stream>>>(
      Qhi, Qlo, Khi, Klo, kcount, scores);
  softmax_kernel<<<NTOK / 4, 256, 0, stream>>>(scores, kcount);
  pv_kernel<<<8 * 16 * BATCH, 256, 0, stream>>>(
      (const u16*)scores, Vt, kcount, out);
}